// Round 10
// baseline (301.357 us; speedup 1.0000x reference)
//
#include <hip/hip_runtime.h>
#include <math.h>
#include <utility>

typedef __attribute__((ext_vector_type(8))) short    bf16x8;
typedef __attribute__((ext_vector_type(4))) float    f32x4;
typedef __attribute__((ext_vector_type(2))) unsigned u32x2;
typedef __attribute__((ext_vector_type(4))) unsigned u32x4;

template<int I, int N, class F>
__device__ __forceinline__ void sfor(F&& f) {
    if constexpr (I < N) { f(std::integral_constant<int, I>{}); sfor<I + 1, N>(static_cast<F&&>(f)); }
}

#define NPT    50000
#define NTILES 6250     // 400000 pts / 64 per tile, exact
#define ZIN_S  40       // shorts per zin row (80 B = 5*16B)
#define Z_S    136      // shorts per z1/z2 row (272 B = 17*16B)
#define LOG2E  1.4426950408889634f

static __device__ __forceinline__ unsigned short bf16r(float f) {   // RNE f32->bf16
    unsigned u = __builtin_bit_cast(unsigned, f);
    u += 0x7FFFu + ((u >> 16) & 1u);
    return (unsigned short)(u >> 16);
}

#if defined(__has_builtin)
#if __has_builtin(__builtin_amdgcn_cvt_pk_bf16_f32)
#define HAVE_CVT_PK_BF16 1
#endif
#if __has_builtin(__builtin_amdgcn_exp2f) && __has_builtin(__builtin_amdgcn_rcpf)
#define HAVE_RAW_TRANS 1
#endif
#endif

static __device__ __forceinline__ unsigned packbf(float a, float b) {
#ifdef HAVE_CVT_PK_BF16
    return __builtin_bit_cast(unsigned, __builtin_amdgcn_cvt_pk_bf16_f32(a, b));
#else
    return (unsigned)bf16r(a) | ((unsigned)bf16r(b) << 16);
#endif
}

#ifdef HAVE_RAW_TRANS
static __device__ __forceinline__ float fexp2(float x) { return __builtin_amdgcn_exp2f(x); }
static __device__ __forceinline__ float frcp(float x)  { return __builtin_amdgcn_rcpf(x); }
#else
static __device__ __forceinline__ float fexp2(float x) { return __exp2f(x); }
static __device__ __forceinline__ float frcp(float x)  { return __frcp_rn(x); }
#endif

// g-weights pre-scaled by -log2e: gate = relu(h * sigmoid(g)) = max(h*rcp(1+2^g'),0)
static __device__ __forceinline__ float gate(float h, float gp) {
    return fmaxf(h * frcp(1.f + fexp2(gp)), 0.f);
}
// out-weights pre-scaled by 2*log2e: tanh(v)*0.5 = 0.5 - rcp(2^v' + 1)
static __device__ __forceinline__ float khalf(float vp) {
    return 0.5f - frcp(fexp2(vp) + 1.f);
}

static __device__ __forceinline__ bf16x8 pack8s(const float* p, float s) { // p 16B-aligned
    f32x4 lo = *reinterpret_cast<const f32x4*>(p);
    f32x4 hi = *reinterpret_cast<const f32x4*>(p + 4);
    u32x4 u = { packbf(lo[0]*s, lo[1]*s), packbf(lo[2]*s, lo[3]*s),
                packbf(hi[0]*s, hi[1]*s), packbf(hi[2]*s, hi[3]*s) };
    return __builtin_bit_cast(bf16x8, u);
}
static __device__ __forceinline__ f32x4 mfma16(bf16x8 a, bf16x8 b, f32x4 c) {
    return __builtin_amdgcn_mfma_f32_16x16x32_bf16(a, b, c, 0, 0, 0);
}

// Block = 512 thr = 8 waves, one 64-point tile per block.
// Wave w owns channel rows [16w,16w+16); waves 0-3 own points [16w,16w+16).
// Round-10: nt loops fully unrolled (sfor) with hoisted per-lane LDS base
// pointers -> ds_read/write use constant offset: immediates (<=13.2KB, fits
// 16-bit field). Kills the base+nt*stride VALU recompute that made R9's
// VALU-busy 2x the hand count. (512,4): persistent regs now only ~44
// (a2 frags + state; biases/aow/a1 in LDS), peak ~100 < 128 cap.
__global__ __launch_bounds__(512, 4) void node_rk4_mfma(
    const float* __restrict__ x0,
    const float* __restrict__ h1_w, const float* __restrict__ h1_b,
    const float* __restrict__ g1_w, const float* __restrict__ g1_b,
    const float* __restrict__ h2_w, const float* __restrict__ h2_b,
    const float* __restrict__ g2_w, const float* __restrict__ g2_b,
    const float* __restrict__ out_w, const float* __restrict__ out_b,
    float* __restrict__ y)
{
    __shared__ __align__(16) short zin[64 * ZIN_S];
    __shared__ __align__(16) short z1s[64 * Z_S];
    __shared__ __align__(16) short z2s[64 * Z_S];
    __shared__ __align__(16) short aow_s[4 * 64 * 8];    // out-layer A-frags [ks][lane]
    __shared__ __align__(16) float bias_s[4 * 128 + 16]; // h1,g1',h2,g2' + vob'
    __shared__ __align__(8)  unsigned a1_s[2 * 256];     // layer1 A rows (h, g')

    const int tid  = threadIdx.x;
    const int w    = tid >> 6;        // wave id 0..7
    const int lane = tid & 63;
    const int q    = lane >> 4;       // quad 0..3
    const int m    = lane & 15;       // MFMA row (A) / col (B,C)

    // ---------------- weight preload (once per block) ----------------
    const int row = 16 * w + m;                 // this lane's A-row (channel)
    bf16x8 a2h[4], a2g[4];                      // layer2 A-frags per k-step (32 regs)
    sfor<0, 4>([&](auto KS) {
        constexpr int ks = KS.value;
        a2h[ks] = pack8s(h2_w + row * 128 + ks * 32 + q * 8, 1.0f);
        a2g[ks] = pack8s(g2_w + row * 128 + ks * 32 + q * 8, -LOG2E);
    });
    // layer1 A rows -> LDS compact (4 bf16 = 8 B per channel, h then g)
    if (tid < 128) {
        const f32x4 t1 = *reinterpret_cast<const f32x4*>(h1_w + tid * 4);
        const f32x4 t2 = *reinterpret_cast<const f32x4*>(g1_w + tid * 4);
        a1_s[tid * 2]           = packbf(t1[0], t1[1]);
        a1_s[tid * 2 + 1]       = packbf(t1[2], t1[3]);
        a1_s[256 + tid * 2]     = packbf(t2[0] * -LOG2E, t2[1] * -LOG2E);
        a1_s[256 + tid * 2 + 1] = packbf(t2[2] * -LOG2E, t2[3] * -LOG2E);
    }
    // out-layer A-frags -> LDS (wave 0 builds; lane-linear, conflict-free reads)
    if (w == 0) {
        sfor<0, 4>([&](auto KS) {
            constexpr int ks = KS.value;
            bf16x8 t = {0,0,0,0,0,0,0,0};
            if (m < 3) t = pack8s(out_w + m * 128 + ks * 32 + q * 8, 2.f * LOG2E);
            *reinterpret_cast<bf16x8*>(&aow_s[(ks * 64 + lane) * 8]) = t;
        });
    }
    // biases -> LDS (C-frag reads are wave-broadcast)
    if (tid < 128) {
        bias_s[tid]       = h1_b[tid];
        bias_s[128 + tid] = g1_b[tid] * -LOG2E;
        bias_s[256 + tid] = h2_b[tid];
        bias_s[384 + tid] = g2_b[tid] * -LOG2E;
    }
    if (tid < 16) bias_s[512 + tid] = (tid < 3) ? out_b[tid] * (2.f * LOG2E) : 0.f;

    // zero zin (pad rows k=4..31 must be 0 for the K-padded layer1 MFMA)
    for (int i = tid; i < 64 * ZIN_S / 2; i += 512) ((unsigned*)zin)[i] = 0u;
    __syncthreads();

    const float third = 1.0f / 3.0f;
    const int tile = blockIdx.x;
    const int cb4 = 16 * w + 4 * q;   // this lane's C-frag channel base

    // ---- hoisted per-lane LDS base pointers (stage-invariant); all stage-loop
    // accesses are base + compile-time offset -> ds_* offset: immediates ----
    const short* zin_rd = &zin[m * ZIN_S + q * 8];            // + nt*16*ZIN_S
    short*       zin_wr = &zin[(w * 16 + m) * ZIN_S];         // lanes<16, w<4
    const short* z1_rd  = &z1s[m * Z_S + q * 8];              // + nt*16*Z_S + ks*32
    short*       z1_wr  = &z1s[m * Z_S + cb4];                // + nt*16*Z_S
    short*       z2_wr  = &z2s[m * Z_S + cb4];
    const short* z2_rd  = &z2s[(w * 16 + m) * Z_S + q * 8];   // + ks*32 (w<4)
    const short* aow_rd = &aow_s[lane * 8];                   // + ks*64*8
    const float* bs1h = &bias_s[cb4];
    const float* bs1g = &bias_s[128 + cb4];
    const float* bs2h = &bias_s[256 + cb4];
    const float* bs2g = &bias_s[384 + cb4];
    const float* bsov = &bias_s[512 + 4 * q];

    // RK4 state: waves 0-3, lanes 0-15 (point = tile*64 + w*16 + lane)
    float xc0 = 0.f, xc1 = 0.f, xc2 = 0.f;
    int gbase = 0;
    if (w < 4 && lane < 16) {
        const int pg = tile * 64 + w * 16 + lane;
        const int bb = pg / NPT;
        const int nn = pg - bb * NPT;
        gbase = bb * 3 * NPT + nn;
        xc0 = x0[gbase]; xc1 = x0[gbase + NPT]; xc2 = x0[gbase + 2 * NPT];
    }
    float k1x=0,k1y=0,k1z=0, k2x=0,k2y=0,k2z=0, k3x=0,k3y=0,k3z=0;
    float ax=0, ay=0, az=0;

    #pragma unroll 1
    for (int s = 0; s < 4; ++s) {
        // ---- stage input -> zin (B-frag rows; owner lanes only) ----
        if (w < 4 && lane < 16) {
            float zi0, zi1, zi2, tt;
            if (s == 0)      { zi0 = xc0; zi1 = xc1; zi2 = xc2; tt = 0.f; }
            else if (s == 1) { zi0 = fmaf(k1x, third, xc0);
                               zi1 = fmaf(k1y, third, xc1);
                               zi2 = fmaf(k1z, third, xc2); tt = third; }
            else if (s == 2) { zi0 = xc0 + (k2x - k1x * third);
                               zi1 = xc1 + (k2y - k1y * third);
                               zi2 = xc2 + (k2z - k1z * third); tt = 2.f * third; }
            else             { zi0 = xc0 + (k1x - k2x + k3x);
                               zi1 = xc1 + (k1y - k2y + k3y);
                               zi2 = xc2 + (k1z - k2z + k3z); tt = 1.f; }
            u32x2 pk = { packbf(zi0, zi1), packbf(zi2, tt) };
            *reinterpret_cast<u32x2*>(zin_wr) = pk;
        }
        __syncthreads();

        // ---- layer 1 (4->128, K-padded MFMA); A-frags rebuilt from LDS ----
        {
            bf16x8 a1h = {0,0,0,0,0,0,0,0}, a1g = {0,0,0,0,0,0,0,0};
            if (q == 0) {
                u32x2 th = *reinterpret_cast<const u32x2*>(&a1_s[row * 2]);
                u32x2 tg = *reinterpret_cast<const u32x2*>(&a1_s[256 + row * 2]);
                u32x4 uh = { th[0], th[1], 0u, 0u };
                u32x4 ug = { tg[0], tg[1], 0u, 0u };
                a1h = __builtin_bit_cast(bf16x8, uh);
                a1g = __builtin_bit_cast(bf16x8, ug);
            }
            const f32x4 b1h = *reinterpret_cast<const f32x4*>(bs1h);
            const f32x4 b1g = *reinterpret_cast<const f32x4*>(bs1g);
            sfor<0, 4>([&](auto NT) {
                constexpr int nt = NT.value;
                bf16x8 bf = *reinterpret_cast<const bf16x8*>(zin_rd + nt * 16 * ZIN_S);
                f32x4 ch = mfma16(a1h, bf, b1h);
                f32x4 cg = mfma16(a1g, bf, b1g);
                u32x2 pk = { packbf(gate(ch[0], cg[0]), gate(ch[1], cg[1])),
                             packbf(gate(ch[2], cg[2]), gate(ch[3], cg[3])) };
                *reinterpret_cast<u32x2*>(z1_wr + nt * 16 * Z_S) = pk;
            });
        }
        __syncthreads();

        // ---- layer 2 (128->128); fully unrolled, bias rides in as C ----
        {
            const f32x4 b2h = *reinterpret_cast<const f32x4*>(bs2h);
            const f32x4 b2g = *reinterpret_cast<const f32x4*>(bs2g);
            f32x4 ch[4], cg[4];
            sfor<0, 4>([&](auto NT) {
                constexpr int nt = NT.value;
                bf16x8 bf = *reinterpret_cast<const bf16x8*>(z1_rd + nt * 16 * Z_S);
                ch[nt] = mfma16(a2h[0], bf, b2h);
                cg[nt] = mfma16(a2g[0], bf, b2g);
            });
            sfor<1, 4>([&](auto KS) {
                constexpr int ks = KS.value;
                sfor<0, 4>([&](auto NT) {
                    constexpr int nt = NT.value;
                    bf16x8 bf = *reinterpret_cast<const bf16x8*>(z1_rd + nt * 16 * Z_S + ks * 32);
                    ch[nt] = mfma16(a2h[ks], bf, ch[nt]);
                    cg[nt] = mfma16(a2g[ks], bf, cg[nt]);
                });
            });
            sfor<0, 4>([&](auto NT) {
                constexpr int nt = NT.value;
                u32x2 pk = { packbf(gate(ch[nt][0], cg[nt][0]), gate(ch[nt][1], cg[nt][1])),
                             packbf(gate(ch[nt][2], cg[nt][2]), gate(ch[nt][3], cg[nt][3])) };
                *reinterpret_cast<u32x2*>(z2_wr + nt * 16 * Z_S) = pk;
            });
        }
        __syncthreads();

        // ---- out layer (128->3, M padded to 16); waves 0-3, 16 pts each ----
        if (w < 4) {
            f32x4 vc = *reinterpret_cast<const f32x4*>(bsov);
            sfor<0, 4>([&](auto KS) {
                constexpr int ks = KS.value;
                bf16x8 af = *reinterpret_cast<const bf16x8*>(aow_rd + ks * 64 * 8);
                bf16x8 bf = *reinterpret_cast<const bf16x8*>(z2_rd + ks * 32);
                vc = mfma16(af, bf, vc);
            });
            // channels live in quad-0 regs 0..2; khalf = tanh*0.5 (scale folded)
            const float kx = khalf(vc[0]);
            const float ky = khalf(vc[1]);
            const float kz = khalf(vc[2]);

            if (s == 0)      { k1x=kx;k1y=ky;k1z=kz; ax=kx;ay=ky;az=kz; }
            else if (s == 1) { k2x=kx;k2y=ky;k2z=kz;
                               ax=fmaf(3.f,kx,ax); ay=fmaf(3.f,ky,ay); az=fmaf(3.f,kz,az); }
            else if (s == 2) { k3x=kx;k3y=ky;k3z=kz;
                               ax=fmaf(3.f,kx,ax); ay=fmaf(3.f,ky,ay); az=fmaf(3.f,kz,az); }
            else             { ax+=kx; ay+=ky; az+=kz; }
        }
    }

    if (w < 4 && lane < 16) {
        y[gbase]           = fmaf(0.125f, ax, xc0);
        y[gbase + NPT]     = fmaf(0.125f, ay, xc1);
        y[gbase + 2 * NPT] = fmaf(0.125f, az, xc2);
    }
}

extern "C" void kernel_launch(void* const* d_in, const int* in_sizes, int n_in,
                              void* d_out, int out_size, void* d_ws, size_t ws_size,
                              hipStream_t stream) {
    (void)in_sizes; (void)n_in; (void)d_ws; (void)ws_size; (void)out_size;
    const float* x0    = (const float*)d_in[0];
    const float* h1_w  = (const float*)d_in[1];
    const float* h1_b  = (const float*)d_in[2];
    const float* g1_w  = (const float*)d_in[3];
    const float* g1_b  = (const float*)d_in[4];
    const float* h2_w  = (const float*)d_in[5];
    const float* h2_b  = (const float*)d_in[6];
    const float* g2_w  = (const float*)d_in[7];
    const float* g2_b  = (const float*)d_in[8];
    const float* out_w = (const float*)d_in[9];
    const float* out_b = (const float*)d_in[10];
    float* y = (float*)d_out;

    // one 64-pt tile per 512-thread block
    node_rk4_mfma<<<NTILES, 512, 0, stream>>>(
        x0, h1_w, h1_b, g1_w, g1_b, h2_w, h2_b, g2_w, g2_b, out_w, out_b, y);
}

// Round 11
// 295.243 us; speedup vs baseline: 1.0207x; 1.0207x over previous
//
#include <hip/hip_runtime.h>
#include <math.h>
#include <utility>

typedef __attribute__((ext_vector_type(8))) short    bf16x8;
typedef __attribute__((ext_vector_type(4))) float    f32x4;
typedef __attribute__((ext_vector_type(2))) unsigned u32x2;
typedef __attribute__((ext_vector_type(4))) unsigned u32x4;

template<int I, int N, class F>
__device__ __forceinline__ void sfor(F&& f) {
    if constexpr (I < N) { f(std::integral_constant<int, I>{}); sfor<I + 1, N>(static_cast<F&&>(f)); }
}

#define NPT    50000
#define NTILES 6250     // 400000 pts / 64 per tile, exact
#define TPB    2        // tiles per block
#define ZIN_S  40       // shorts per zin row (80 B = 5*16B)
#define Z_S    136      // shorts per z1/z2 row (272 B = 17*16B)
#define LOG2E  1.4426950408889634f

static __device__ __forceinline__ unsigned short bf16r(float f) {   // RNE f32->bf16
    unsigned u = __builtin_bit_cast(unsigned, f);
    u += 0x7FFFu + ((u >> 16) & 1u);
    return (unsigned short)(u >> 16);
}

#if defined(__has_builtin)
#if __has_builtin(__builtin_amdgcn_cvt_pk_bf16_f32)
#define HAVE_CVT_PK_BF16 1
#endif
#if __has_builtin(__builtin_amdgcn_exp2f) && __has_builtin(__builtin_amdgcn_rcpf)
#define HAVE_RAW_TRANS 1
#endif
#endif

static __device__ __forceinline__ unsigned packbf(float a, float b) {
#ifdef HAVE_CVT_PK_BF16
    return __builtin_bit_cast(unsigned, __builtin_amdgcn_cvt_pk_bf16_f32(a, b));
#else
    return (unsigned)bf16r(a) | ((unsigned)bf16r(b) << 16);
#endif
}

#ifdef HAVE_RAW_TRANS
static __device__ __forceinline__ float fexp2(float x) { return __builtin_amdgcn_exp2f(x); }
static __device__ __forceinline__ float frcp(float x)  { return __builtin_amdgcn_rcpf(x); }
#else
static __device__ __forceinline__ float fexp2(float x) { return __exp2f(x); }
static __device__ __forceinline__ float frcp(float x)  { return __frcp_rn(x); }
#endif

// paired-gate: two gated activations sharing ONE v_rcp via reciprocal-product.
// gate_i = relu(h_i * sigmoid(g_i)); g pre-scaled by -log2e so sigma = 1/(1+2^gp).
// sigma0 = p1*ip, sigma1 = p0*ip with ip = rcp(p0*p1). p in (1, 2^~45] -> no overflow.
static __device__ __forceinline__ unsigned gate2(float h0, float gp0, float h1, float gp1) {
    float p0 = 1.f + fexp2(gp0);
    float p1 = 1.f + fexp2(gp1);
    float ip = frcp(p0 * p1);
    float z0 = fmaxf(h0 * (p1 * ip), 0.f);
    float z1 = fmaxf(h1 * (p0 * ip), 0.f);
    return packbf(z0, z1);
}

static __device__ __forceinline__ bf16x8 pack8s(const float* p, float s) { // p 16B-aligned
    f32x4 lo = *reinterpret_cast<const f32x4*>(p);
    f32x4 hi = *reinterpret_cast<const f32x4*>(p + 4);
    u32x4 u = { packbf(lo[0]*s, lo[1]*s), packbf(lo[2]*s, lo[3]*s),
                packbf(hi[0]*s, hi[1]*s), packbf(hi[2]*s, hi[3]*s) };
    return __builtin_bit_cast(bf16x8, u);
}
static __device__ __forceinline__ f32x4 mfma16(bf16x8 a, bf16x8 b, f32x4 c) {
    return __builtin_amdgcn_mfma_f32_16x16x32_bf16(a, b, c, 0, 0, 0);
}

// Block = 512 thr = 8 waves, TWO 64-point tiles per block (preload amortized).
// Wave w owns channel rows [16w,16w+16); waves 0-3 own points [16w,16w+16).
// Round-11: paired-rcp sigmoid/tanh (trans count -25%), 2 tiles/block.
__global__ __launch_bounds__(512, 4) void node_rk4_mfma(
    const float* __restrict__ x0,
    const float* __restrict__ h1_w, const float* __restrict__ h1_b,
    const float* __restrict__ g1_w, const float* __restrict__ g1_b,
    const float* __restrict__ h2_w, const float* __restrict__ h2_b,
    const float* __restrict__ g2_w, const float* __restrict__ g2_b,
    const float* __restrict__ out_w, const float* __restrict__ out_b,
    float* __restrict__ y)
{
    __shared__ __align__(16) short zin[64 * ZIN_S];
    __shared__ __align__(16) short z1s[64 * Z_S];
    __shared__ __align__(16) short z2s[64 * Z_S];
    __shared__ __align__(16) short aow_s[4 * 64 * 8];    // out-layer A-frags [ks][lane]
    __shared__ __align__(16) float bias_s[4 * 128 + 16]; // h1,g1',h2,g2' + vob'
    __shared__ __align__(8)  unsigned a1_s[2 * 256];     // layer1 A rows (h, g')

    const int tid  = threadIdx.x;
    const int w    = tid >> 6;        // wave id 0..7
    const int lane = tid & 63;
    const int q    = lane >> 4;       // quad 0..3
    const int m    = lane & 15;       // MFMA row (A) / col (B,C)

    // ---------------- weight preload (once per block, reused by TPB tiles) ----
    const int row = 16 * w + m;                 // this lane's A-row (channel)
    bf16x8 a2h[4], a2g[4];                      // layer2 A-frags per k-step (32 regs)
    sfor<0, 4>([&](auto KS) {
        constexpr int ks = KS.value;
        a2h[ks] = pack8s(h2_w + row * 128 + ks * 32 + q * 8, 1.0f);
        a2g[ks] = pack8s(g2_w + row * 128 + ks * 32 + q * 8, -LOG2E);
    });
    // layer1 A rows -> LDS compact (4 bf16 = 8 B per channel, h then g)
    if (tid < 128) {
        const f32x4 t1 = *reinterpret_cast<const f32x4*>(h1_w + tid * 4);
        const f32x4 t2 = *reinterpret_cast<const f32x4*>(g1_w + tid * 4);
        a1_s[tid * 2]           = packbf(t1[0], t1[1]);
        a1_s[tid * 2 + 1]       = packbf(t1[2], t1[3]);
        a1_s[256 + tid * 2]     = packbf(t2[0] * -LOG2E, t2[1] * -LOG2E);
        a1_s[256 + tid * 2 + 1] = packbf(t2[2] * -LOG2E, t2[3] * -LOG2E);
    }
    // out-layer A-frags -> LDS (wave 0 builds; lane-linear, conflict-free reads)
    if (w == 0) {
        sfor<0, 4>([&](auto KS) {
            constexpr int ks = KS.value;
            bf16x8 t = {0,0,0,0,0,0,0,0};
            if (m < 3) t = pack8s(out_w + m * 128 + ks * 32 + q * 8, 2.f * LOG2E);
            *reinterpret_cast<bf16x8*>(&aow_s[(ks * 64 + lane) * 8]) = t;
        });
    }
    // biases -> LDS (C-frag reads are wave-broadcast)
    if (tid < 128) {
        bias_s[tid]       = h1_b[tid];
        bias_s[128 + tid] = g1_b[tid] * -LOG2E;
        bias_s[256 + tid] = h2_b[tid];
        bias_s[384 + tid] = g2_b[tid] * -LOG2E;
    }
    if (tid < 16) bias_s[512 + tid] = (tid < 3) ? out_b[tid] * (2.f * LOG2E) : 0.f;

    // zero zin once (pad rows k=4..31 stay 0 across tiles; staging only
    // rewrites the first 8 B of each row)
    for (int i = tid; i < 64 * ZIN_S / 2; i += 512) ((unsigned*)zin)[i] = 0u;
    __syncthreads();

    const float third = 1.0f / 3.0f;
    const int cb4 = 16 * w + 4 * q;   // this lane's C-frag channel base

    // hoisted per-lane LDS base pointers (stage/tile-invariant)
    const short* zin_rd = &zin[m * ZIN_S + q * 8];            // + nt*16*ZIN_S
    short*       zin_wr = &zin[(w * 16 + m) * ZIN_S];         // lanes<16, w<4
    const short* z1_rd  = &z1s[m * Z_S + q * 8];              // + nt*16*Z_S + ks*32
    short*       z1_wr  = &z1s[m * Z_S + cb4];                // + nt*16*Z_S
    short*       z2_wr  = &z2s[m * Z_S + cb4];
    const short* z2_rd  = &z2s[(w * 16 + m) * Z_S + q * 8];   // + ks*32 (w<4)
    const short* aow_rd = &aow_s[lane * 8];                   // + ks*64*8
    const float* bs1h = &bias_s[cb4];
    const float* bs1g = &bias_s[128 + cb4];
    const float* bs2h = &bias_s[256 + cb4];
    const float* bs2g = &bias_s[384 + cb4];
    const float* bsov = &bias_s[512 + 4 * q];

    #pragma unroll 1
    for (int t2 = 0; t2 < TPB; ++t2) {
        const int tile = blockIdx.x * TPB + t2;

        // RK4 state: waves 0-3, lanes 0-15 (point = tile*64 + w*16 + lane)
        float xc0 = 0.f, xc1 = 0.f, xc2 = 0.f;
        int gbase = 0;
        if (w < 4 && lane < 16) {
            const int pg = tile * 64 + w * 16 + lane;
            const int bb = pg / NPT;
            const int nn = pg - bb * NPT;
            gbase = bb * 3 * NPT + nn;
            xc0 = x0[gbase]; xc1 = x0[gbase + NPT]; xc2 = x0[gbase + 2 * NPT];
        }
        float k1x=0,k1y=0,k1z=0, k2x=0,k2y=0,k2z=0, k3x=0,k3y=0,k3z=0;
        float ax=0, ay=0, az=0;

        #pragma unroll 1
        for (int s = 0; s < 4; ++s) {
            // ---- stage input -> zin (B-frag rows; owner lanes only) ----
            if (w < 4 && lane < 16) {
                float zi0, zi1, zi2, tt;
                if (s == 0)      { zi0 = xc0; zi1 = xc1; zi2 = xc2; tt = 0.f; }
                else if (s == 1) { zi0 = fmaf(k1x, third, xc0);
                                   zi1 = fmaf(k1y, third, xc1);
                                   zi2 = fmaf(k1z, third, xc2); tt = third; }
                else if (s == 2) { zi0 = xc0 + (k2x - k1x * third);
                                   zi1 = xc1 + (k2y - k1y * third);
                                   zi2 = xc2 + (k2z - k1z * third); tt = 2.f * third; }
                else             { zi0 = xc0 + (k1x - k2x + k3x);
                                   zi1 = xc1 + (k1y - k2y + k3y);
                                   zi2 = xc2 + (k1z - k2z + k3z); tt = 1.f; }
                u32x2 pk = { packbf(zi0, zi1), packbf(zi2, tt) };
                *reinterpret_cast<u32x2*>(zin_wr) = pk;
            }
            __syncthreads();

            // ---- layer 1 (4->128, K-padded MFMA); A-frags rebuilt from LDS ----
            {
                bf16x8 a1h = {0,0,0,0,0,0,0,0}, a1g = {0,0,0,0,0,0,0,0};
                if (q == 0) {
                    u32x2 th = *reinterpret_cast<const u32x2*>(&a1_s[row * 2]);
                    u32x2 tg = *reinterpret_cast<const u32x2*>(&a1_s[256 + row * 2]);
                    u32x4 uh = { th[0], th[1], 0u, 0u };
                    u32x4 ug = { tg[0], tg[1], 0u, 0u };
                    a1h = __builtin_bit_cast(bf16x8, uh);
                    a1g = __builtin_bit_cast(bf16x8, ug);
                }
                const f32x4 b1h = *reinterpret_cast<const f32x4*>(bs1h);
                const f32x4 b1g = *reinterpret_cast<const f32x4*>(bs1g);
                sfor<0, 4>([&](auto NT) {
                    constexpr int nt = NT.value;
                    bf16x8 bf = *reinterpret_cast<const bf16x8*>(zin_rd + nt * 16 * ZIN_S);
                    f32x4 ch = mfma16(a1h, bf, b1h);
                    f32x4 cg = mfma16(a1g, bf, b1g);
                    u32x2 pk = { gate2(ch[0], cg[0], ch[1], cg[1]),
                                 gate2(ch[2], cg[2], ch[3], cg[3]) };
                    *reinterpret_cast<u32x2*>(z1_wr + nt * 16 * Z_S) = pk;
                });
            }
            __syncthreads();

            // ---- layer 2 (128->128); fully unrolled, bias rides in as C ----
            {
                const f32x4 b2h = *reinterpret_cast<const f32x4*>(bs2h);
                const f32x4 b2g = *reinterpret_cast<const f32x4*>(bs2g);
                f32x4 ch[4], cg[4];
                sfor<0, 4>([&](auto NT) {
                    constexpr int nt = NT.value;
                    bf16x8 bf = *reinterpret_cast<const bf16x8*>(z1_rd + nt * 16 * Z_S);
                    ch[nt] = mfma16(a2h[0], bf, b2h);
                    cg[nt] = mfma16(a2g[0], bf, b2g);
                });
                sfor<1, 4>([&](auto KS) {
                    constexpr int ks = KS.value;
                    sfor<0, 4>([&](auto NT) {
                        constexpr int nt = NT.value;
                        bf16x8 bf = *reinterpret_cast<const bf16x8*>(z1_rd + nt * 16 * Z_S + ks * 32);
                        ch[nt] = mfma16(a2h[ks], bf, ch[nt]);
                        cg[nt] = mfma16(a2g[ks], bf, cg[nt]);
                    });
                });
                sfor<0, 4>([&](auto NT) {
                    constexpr int nt = NT.value;
                    u32x2 pk = { gate2(ch[nt][0], cg[nt][0], ch[nt][1], cg[nt][1]),
                                 gate2(ch[nt][2], cg[nt][2], ch[nt][3], cg[nt][3]) };
                    *reinterpret_cast<u32x2*>(z2_wr + nt * 16 * Z_S) = pk;
                });
            }
            __syncthreads();

            // ---- out layer (128->3, M padded to 16); waves 0-3, 16 pts each ----
            if (w < 4) {
                f32x4 vc = *reinterpret_cast<const f32x4*>(bsov);
                sfor<0, 4>([&](auto KS) {
                    constexpr int ks = KS.value;
                    bf16x8 af = *reinterpret_cast<const bf16x8*>(aow_rd + ks * 64 * 8);
                    bf16x8 bf = *reinterpret_cast<const bf16x8*>(z2_rd + ks * 32);
                    vc = mfma16(af, bf, vc);
                });
                // khalf = tanh*0.5 = 0.5 - 1/p, p = 2^v' + 1 (scale folded into
                // out weights). Pair kx,ky through one rcp; kz single.
                const float px = fexp2(vc[0]) + 1.f;
                const float py = fexp2(vc[1]) + 1.f;
                const float ipxy = frcp(px * py);
                const float kx = 0.5f - py * ipxy;
                const float ky = 0.5f - px * ipxy;
                const float kz = 0.5f - frcp(fexp2(vc[2]) + 1.f);

                if (s == 0)      { k1x=kx;k1y=ky;k1z=kz; ax=kx;ay=ky;az=kz; }
                else if (s == 1) { k2x=kx;k2y=ky;k2z=kz;
                                   ax=fmaf(3.f,kx,ax); ay=fmaf(3.f,ky,ay); az=fmaf(3.f,kz,az); }
                else if (s == 2) { k3x=kx;k3y=ky;k3z=kz;
                                   ax=fmaf(3.f,kx,ax); ay=fmaf(3.f,ky,ay); az=fmaf(3.f,kz,az); }
                else             { ax+=kx; ay+=ky; az+=kz; }
            }
        }

        if (w < 4 && lane < 16) {
            y[gbase]           = fmaf(0.125f, ax, xc0);
            y[gbase + NPT]     = fmaf(0.125f, ay, xc1);
            y[gbase + 2 * NPT] = fmaf(0.125f, az, xc2);
        }
        __syncthreads();   // zin/z2 reuse safety across tiles
    }
}

extern "C" void kernel_launch(void* const* d_in, const int* in_sizes, int n_in,
                              void* d_out, int out_size, void* d_ws, size_t ws_size,
                              hipStream_t stream) {
    (void)in_sizes; (void)n_in; (void)d_ws; (void)ws_size; (void)out_size;
    const float* x0    = (const float*)d_in[0];
    const float* h1_w  = (const float*)d_in[1];
    const float* h1_b  = (const float*)d_in[2];
    const float* g1_w  = (const float*)d_in[3];
    const float* g1_b  = (const float*)d_in[4];
    const float* h2_w  = (const float*)d_in[5];
    const float* h2_b  = (const float*)d_in[6];
    const float* g2_w  = (const float*)d_in[7];
    const float* g2_b  = (const float*)d_in[8];
    const float* out_w = (const float*)d_in[9];
    const float* out_b = (const float*)d_in[10];
    float* y = (float*)d_out;

    // two 64-pt tiles per 512-thread block
    node_rk4_mfma<<<NTILES / TPB, 512, 0, stream>>>(
        x0, h1_w, h1_b, g1_w, g1_b, h2_w, h2_b, g2_w, g2_b, out_w, out_b, y);
}

// Round 12
// 289.181 us; speedup vs baseline: 1.0421x; 1.0210x over previous
//
#include <hip/hip_runtime.h>
#include <math.h>
#include <utility>

typedef __attribute__((ext_vector_type(8))) short    bf16x8;
typedef __attribute__((ext_vector_type(4))) float    f32x4;
typedef __attribute__((ext_vector_type(2))) float    f32x2;
typedef __attribute__((ext_vector_type(2))) unsigned u32x2;
typedef __attribute__((ext_vector_type(4))) unsigned u32x4;

template<int I, int N, class F>
__device__ __forceinline__ void sfor(F&& f) {
    if constexpr (I < N) { f(std::integral_constant<int, I>{}); sfor<I + 1, N>(static_cast<F&&>(f)); }
}

#define NPT    50000
#define NTILES 6250     // 400000 pts / 64 per tile, exact
#define TPB    2        // tiles per block
#define ZIN_S  40       // shorts per zin row (80 B = 5*16B)
#define Z_S    136      // shorts per z1/z2 row (272 B = 17*16B)
#define LOG2E  1.4426950408889634f

static __device__ __forceinline__ unsigned short bf16r(float f) {   // RNE f32->bf16
    unsigned u = __builtin_bit_cast(unsigned, f);
    u += 0x7FFFu + ((u >> 16) & 1u);
    return (unsigned short)(u >> 16);
}

#if defined(__has_builtin)
#if __has_builtin(__builtin_amdgcn_cvt_pk_bf16_f32)
#define HAVE_CVT_PK_BF16 1
#endif
#if __has_builtin(__builtin_amdgcn_exp2f) && __has_builtin(__builtin_amdgcn_rcpf)
#define HAVE_RAW_TRANS 1
#endif
#endif

static __device__ __forceinline__ unsigned packbf(float a, float b) {
#ifdef HAVE_CVT_PK_BF16
    return __builtin_bit_cast(unsigned, __builtin_amdgcn_cvt_pk_bf16_f32(a, b));
#else
    return (unsigned)bf16r(a) | ((unsigned)bf16r(b) << 16);
#endif
}

#ifdef HAVE_RAW_TRANS
static __device__ __forceinline__ float fexp2(float x) { return __builtin_amdgcn_exp2f(x); }
static __device__ __forceinline__ float frcp(float x)  { return __builtin_amdgcn_rcpf(x); }
#else
static __device__ __forceinline__ float fexp2(float x) { return __exp2f(x); }
static __device__ __forceinline__ float frcp(float x)  { return __frcp_rn(x); }
#endif

// paired gated activation, packed-f32 form. g pre-scaled by -log2e so
// sigma_i = 1/(1 + 2^gp_i); one shared v_rcp via reciprocal-product; the
// add/mul/max run as v_pk_*_f32 (float2 ext-vector ops), .yx swizzle folds
// into op_sel. p in (1, 2^~45] -> no overflow, no NaN.
static __device__ __forceinline__ unsigned gate2p(f32x2 h, f32x2 gp) {
    f32x2 e;
    e.x = fexp2(gp.x);
    e.y = fexp2(gp.y);
    f32x2 p = e + 1.f;                                   // v_pk_add_f32
    float ip = frcp(p.x * p.y);
    f32x2 ps = __builtin_shufflevector(p, p, 1, 0);      // op_sel swizzle
    f32x2 z = (h * ps) * ip;                             // v_pk_mul_f32 x2
    z = __builtin_elementwise_max(z, f32x2{0.f, 0.f});   // v_pk_max_f32
    return packbf(z.x, z.y);
}

static __device__ __forceinline__ bf16x8 pack8s(const float* p, float s) { // p 16B-aligned
    f32x4 lo = *reinterpret_cast<const f32x4*>(p);
    f32x4 hi = *reinterpret_cast<const f32x4*>(p + 4);
    u32x4 u = { packbf(lo[0]*s, lo[1]*s), packbf(lo[2]*s, lo[3]*s),
                packbf(hi[0]*s, hi[1]*s), packbf(hi[2]*s, hi[3]*s) };
    return __builtin_bit_cast(bf16x8, u);
}
static __device__ __forceinline__ f32x4 mfma16(bf16x8 a, bf16x8 b, f32x4 c) {
    return __builtin_amdgcn_mfma_f32_16x16x32_bf16(a, b, c, 0, 0, 0);
}

// Block = 512 thr = 8 waves, TWO 64-point tiles per block (preload amortized).
// Wave w owns channel rows [16w,16w+16); waves 0-3 own points [16w,16w+16).
// Round-12: packed-f32 (v_pk_*) gate math; structure unchanged from R11.
__global__ __launch_bounds__(512, 4) void node_rk4_mfma(
    const float* __restrict__ x0,
    const float* __restrict__ h1_w, const float* __restrict__ h1_b,
    const float* __restrict__ g1_w, const float* __restrict__ g1_b,
    const float* __restrict__ h2_w, const float* __restrict__ h2_b,
    const float* __restrict__ g2_w, const float* __restrict__ g2_b,
    const float* __restrict__ out_w, const float* __restrict__ out_b,
    float* __restrict__ y)
{
    __shared__ __align__(16) short zin[64 * ZIN_S];
    __shared__ __align__(16) short z1s[64 * Z_S];
    __shared__ __align__(16) short z2s[64 * Z_S];
    __shared__ __align__(16) short aow_s[4 * 64 * 8];    // out-layer A-frags [ks][lane]
    __shared__ __align__(16) float bias_s[4 * 128 + 16]; // h1,g1',h2,g2' + vob'
    __shared__ __align__(8)  unsigned a1_s[2 * 256];     // layer1 A rows (h, g')

    const int tid  = threadIdx.x;
    const int w    = tid >> 6;        // wave id 0..7
    const int lane = tid & 63;
    const int q    = lane >> 4;       // quad 0..3
    const int m    = lane & 15;       // MFMA row (A) / col (B,C)

    // ---------------- weight preload (once per block, reused by TPB tiles) ----
    const int row = 16 * w + m;                 // this lane's A-row (channel)
    bf16x8 a2h[4], a2g[4];                      // layer2 A-frags per k-step (32 regs)
    sfor<0, 4>([&](auto KS) {
        constexpr int ks = KS.value;
        a2h[ks] = pack8s(h2_w + row * 128 + ks * 32 + q * 8, 1.0f);
        a2g[ks] = pack8s(g2_w + row * 128 + ks * 32 + q * 8, -LOG2E);
    });
    // layer1 A rows -> LDS compact (4 bf16 = 8 B per channel, h then g)
    if (tid < 128) {
        const f32x4 t1 = *reinterpret_cast<const f32x4*>(h1_w + tid * 4);
        const f32x4 t2 = *reinterpret_cast<const f32x4*>(g1_w + tid * 4);
        a1_s[tid * 2]           = packbf(t1[0], t1[1]);
        a1_s[tid * 2 + 1]       = packbf(t1[2], t1[3]);
        a1_s[256 + tid * 2]     = packbf(t2[0] * -LOG2E, t2[1] * -LOG2E);
        a1_s[256 + tid * 2 + 1] = packbf(t2[2] * -LOG2E, t2[3] * -LOG2E);
    }
    // out-layer A-frags -> LDS (wave 0 builds; lane-linear, conflict-free reads)
    if (w == 0) {
        sfor<0, 4>([&](auto KS) {
            constexpr int ks = KS.value;
            bf16x8 t = {0,0,0,0,0,0,0,0};
            if (m < 3) t = pack8s(out_w + m * 128 + ks * 32 + q * 8, 2.f * LOG2E);
            *reinterpret_cast<bf16x8*>(&aow_s[(ks * 64 + lane) * 8]) = t;
        });
    }
    // biases -> LDS (C-frag reads are wave-broadcast)
    if (tid < 128) {
        bias_s[tid]       = h1_b[tid];
        bias_s[128 + tid] = g1_b[tid] * -LOG2E;
        bias_s[256 + tid] = h2_b[tid];
        bias_s[384 + tid] = g2_b[tid] * -LOG2E;
    }
    if (tid < 16) bias_s[512 + tid] = (tid < 3) ? out_b[tid] * (2.f * LOG2E) : 0.f;

    // zero zin once (pad rows k=4..31 stay 0 across tiles; staging only
    // rewrites the first 8 B of each row)
    for (int i = tid; i < 64 * ZIN_S / 2; i += 512) ((unsigned*)zin)[i] = 0u;
    __syncthreads();

    const float third = 1.0f / 3.0f;
    const int cb4 = 16 * w + 4 * q;   // this lane's C-frag channel base

    // hoisted per-lane LDS base pointers (stage/tile-invariant)
    const short* zin_rd = &zin[m * ZIN_S + q * 8];            // + nt*16*ZIN_S
    short*       zin_wr = &zin[(w * 16 + m) * ZIN_S];         // lanes<16, w<4
    const short* z1_rd  = &z1s[m * Z_S + q * 8];              // + nt*16*Z_S + ks*32
    short*       z1_wr  = &z1s[m * Z_S + cb4];                // + nt*16*Z_S
    short*       z2_wr  = &z2s[m * Z_S + cb4];
    const short* z2_rd  = &z2s[(w * 16 + m) * Z_S + q * 8];   // + ks*32 (w<4)
    const short* aow_rd = &aow_s[lane * 8];                   // + ks*64*8
    const float* bs1h = &bias_s[cb4];
    const float* bs1g = &bias_s[128 + cb4];
    const float* bs2h = &bias_s[256 + cb4];
    const float* bs2g = &bias_s[384 + cb4];
    const float* bsov = &bias_s[512 + 4 * q];

    #pragma unroll 1
    for (int t2 = 0; t2 < TPB; ++t2) {
        const int tile = blockIdx.x * TPB + t2;

        // RK4 state: waves 0-3, lanes 0-15 (point = tile*64 + w*16 + lane)
        float xc0 = 0.f, xc1 = 0.f, xc2 = 0.f;
        int gbase = 0;
        if (w < 4 && lane < 16) {
            const int pg = tile * 64 + w * 16 + lane;
            const int bb = pg / NPT;
            const int nn = pg - bb * NPT;
            gbase = bb * 3 * NPT + nn;
            xc0 = x0[gbase]; xc1 = x0[gbase + NPT]; xc2 = x0[gbase + 2 * NPT];
        }
        float k1x=0,k1y=0,k1z=0, k2x=0,k2y=0,k2z=0, k3x=0,k3y=0,k3z=0;
        float ax=0, ay=0, az=0;

        #pragma unroll 1
        for (int s = 0; s < 4; ++s) {
            // ---- stage input -> zin (B-frag rows; owner lanes only) ----
            if (w < 4 && lane < 16) {
                float zi0, zi1, zi2, tt;
                if (s == 0)      { zi0 = xc0; zi1 = xc1; zi2 = xc2; tt = 0.f; }
                else if (s == 1) { zi0 = fmaf(k1x, third, xc0);
                                   zi1 = fmaf(k1y, third, xc1);
                                   zi2 = fmaf(k1z, third, xc2); tt = third; }
                else if (s == 2) { zi0 = xc0 + (k2x - k1x * third);
                                   zi1 = xc1 + (k2y - k1y * third);
                                   zi2 = xc2 + (k2z - k1z * third); tt = 2.f * third; }
                else             { zi0 = xc0 + (k1x - k2x + k3x);
                                   zi1 = xc1 + (k1y - k2y + k3y);
                                   zi2 = xc2 + (k1z - k2z + k3z); tt = 1.f; }
                u32x2 pk = { packbf(zi0, zi1), packbf(zi2, tt) };
                *reinterpret_cast<u32x2*>(zin_wr) = pk;
            }
            __syncthreads();

            // ---- layer 1 (4->128, K-padded MFMA); A-frags rebuilt from LDS ----
            {
                bf16x8 a1h = {0,0,0,0,0,0,0,0}, a1g = {0,0,0,0,0,0,0,0};
                if (q == 0) {
                    u32x2 th = *reinterpret_cast<const u32x2*>(&a1_s[row * 2]);
                    u32x2 tg = *reinterpret_cast<const u32x2*>(&a1_s[256 + row * 2]);
                    u32x4 uh = { th[0], th[1], 0u, 0u };
                    u32x4 ug = { tg[0], tg[1], 0u, 0u };
                    a1h = __builtin_bit_cast(bf16x8, uh);
                    a1g = __builtin_bit_cast(bf16x8, ug);
                }
                const f32x4 b1h = *reinterpret_cast<const f32x4*>(bs1h);
                const f32x4 b1g = *reinterpret_cast<const f32x4*>(bs1g);
                sfor<0, 4>([&](auto NT) {
                    constexpr int nt = NT.value;
                    bf16x8 bf = *reinterpret_cast<const bf16x8*>(zin_rd + nt * 16 * ZIN_S);
                    f32x4 ch = mfma16(a1h, bf, b1h);
                    f32x4 cg = mfma16(a1g, bf, b1g);
                    u32x2 pk = { gate2p(f32x2{ch[0], ch[1]}, f32x2{cg[0], cg[1]}),
                                 gate2p(f32x2{ch[2], ch[3]}, f32x2{cg[2], cg[3]}) };
                    *reinterpret_cast<u32x2*>(z1_wr + nt * 16 * Z_S) = pk;
                });
            }
            __syncthreads();

            // ---- layer 2 (128->128); fully unrolled, bias rides in as C ----
            {
                const f32x4 b2h = *reinterpret_cast<const f32x4*>(bs2h);
                const f32x4 b2g = *reinterpret_cast<const f32x4*>(bs2g);
                f32x4 ch[4], cg[4];
                sfor<0, 4>([&](auto NT) {
                    constexpr int nt = NT.value;
                    bf16x8 bf = *reinterpret_cast<const bf16x8*>(z1_rd + nt * 16 * Z_S);
                    ch[nt] = mfma16(a2h[0], bf, b2h);
                    cg[nt] = mfma16(a2g[0], bf, b2g);
                });
                sfor<1, 4>([&](auto KS) {
                    constexpr int ks = KS.value;
                    sfor<0, 4>([&](auto NT) {
                        constexpr int nt = NT.value;
                        bf16x8 bf = *reinterpret_cast<const bf16x8*>(z1_rd + nt * 16 * Z_S + ks * 32);
                        ch[nt] = mfma16(a2h[ks], bf, ch[nt]);
                        cg[nt] = mfma16(a2g[ks], bf, cg[nt]);
                    });
                });
                sfor<0, 4>([&](auto NT) {
                    constexpr int nt = NT.value;
                    u32x2 pk = { gate2p(f32x2{ch[nt][0], ch[nt][1]}, f32x2{cg[nt][0], cg[nt][1]}),
                                 gate2p(f32x2{ch[nt][2], ch[nt][3]}, f32x2{cg[nt][2], cg[nt][3]}) };
                    *reinterpret_cast<u32x2*>(z2_wr + nt * 16 * Z_S) = pk;
                });
            }
            __syncthreads();

            // ---- out layer (128->3, M padded to 16); waves 0-3, 16 pts each ----
            if (w < 4) {
                f32x4 vc = *reinterpret_cast<const f32x4*>(bsov);
                sfor<0, 4>([&](auto KS) {
                    constexpr int ks = KS.value;
                    bf16x8 af = *reinterpret_cast<const bf16x8*>(aow_rd + ks * 64 * 8);
                    bf16x8 bf = *reinterpret_cast<const bf16x8*>(z2_rd + ks * 32);
                    vc = mfma16(af, bf, vc);
                });
                // khalf = tanh*0.5 = 0.5 - 1/p, p = 2^v' + 1 (scale folded into
                // out weights). Pair kx,ky through one rcp (packed add); kz single.
                f32x2 e; e.x = fexp2(vc[0]); e.y = fexp2(vc[1]);
                f32x2 p = e + 1.f;
                const float ipxy = frcp(p.x * p.y);
                const float kx = 0.5f - p.y * ipxy;
                const float ky = 0.5f - p.x * ipxy;
                const float kz = 0.5f - frcp(fexp2(vc[2]) + 1.f);

                if (s == 0)      { k1x=kx;k1y=ky;k1z=kz; ax=kx;ay=ky;az=kz; }
                else if (s == 1) { k2x=kx;k2y=ky;k2z=kz;
                                   ax=fmaf(3.f,kx,ax); ay=fmaf(3.f,ky,ay); az=fmaf(3.f,kz,az); }
                else if (s == 2) { k3x=kx;k3y=ky;k3z=kz;
                                   ax=fmaf(3.f,kx,ax); ay=fmaf(3.f,ky,ay); az=fmaf(3.f,kz,az); }
                else             { ax+=kx; ay+=ky; az+=kz; }
            }
        }

        if (w < 4 && lane < 16) {
            y[gbase]           = fmaf(0.125f, ax, xc0);
            y[gbase + NPT]     = fmaf(0.125f, ay, xc1);
            y[gbase + 2 * NPT] = fmaf(0.125f, az, xc2);
        }
        __syncthreads();   // zin/z2 reuse safety across tiles
    }
}

extern "C" void kernel_launch(void* const* d_in, const int* in_sizes, int n_in,
                              void* d_out, int out_size, void* d_ws, size_t ws_size,
                              hipStream_t stream) {
    (void)in_sizes; (void)n_in; (void)d_ws; (void)ws_size; (void)out_size;
    const float* x0    = (const float*)d_in[0];
    const float* h1_w  = (const float*)d_in[1];
    const float* h1_b  = (const float*)d_in[2];
    const float* g1_w  = (const float*)d_in[3];
    const float* g1_b  = (const float*)d_in[4];
    const float* h2_w  = (const float*)d_in[5];
    const float* h2_b  = (const float*)d_in[6];
    const float* g2_w  = (const float*)d_in[7];
    const float* g2_b  = (const float*)d_in[8];
    const float* out_w = (const float*)d_in[9];
    const float* out_b = (const float*)d_in[10];
    float* y = (float*)d_out;

    // two 64-pt tiles per 512-thread block
    node_rk4_mfma<<<NTILES / TPB, 512, 0, stream>>>(
        x0, h1_w, h1_b, g1_w, g1_b, h2_w, h2_b, g2_w, g2_b, out_w, out_b, y);
}